// Round 10
// baseline (95.560 us; speedup 1.0000x reference)
//
#include <hip/hip_runtime.h>
#include <hip/hip_bf16.h>

// x[128][768][28][28] f32 -> per-(b,c) ascending-rank-392 of 784 values,
// then med[128][768] @ W[1000][768]^T + bias -> out[128][1000].

#define NROW 784
#define RANKK 392
#define NWAVE 4   // rows (waves) per block

// ---------------- Kernel 1: per-wave exact select ----------------------------
// One 64-lane wave per row; no __syncthreads (wave-order LDS semantics).
// Fast path (covers ~99.4% of N(0,1) rows, verified exact for any row it
// accepts): 5 fixed thresholds {-2,-1,0,1,2}/16; counts come straight from
// __ballot+popcll -> SGPRs (no histogram, no scan, no atomics, no butterfly).
// Winning 1/16-interval (m ~= 19) is ballot+mbcnt compacted into a 72-float
// LDS buffer; float4-broadcast finisher with scalar loop bounds.
// Fallback (rare / adversarial): register-only 32-step bitwise bisection on
// monotone-sortable keys -- exact for arbitrary data, zero LDS.
__global__ __launch_bounds__(256) void kth_select_kernel(
    const float* __restrict__ x, float* __restrict__ med) {
  __shared__ __align__(16) float cand[NWAVE][72];   // 1152 B total

  const int tid  = threadIdx.x;
  const int lane = tid & 63;
  const int w    = tid >> 6;
  const int row  = blockIdx.x * NWAVE + w;
  const float4* src4 = (const float4*)(x + (size_t)row * NROW);
  const float inf = __int_as_float(0x7f800000);

  // ---- load row: 196 float4 spread as {lane, 64+lane, 128+lane, 192+lane<4}
  float4 f0 = src4[lane];
  float4 f1 = src4[64 + lane];
  float4 f2 = src4[128 + lane];
  const bool v3 = (lane < 4);
  float4 f3 = make_float4(inf, inf, inf, inf);   // +INF pads: inert everywhere
  if (v3) f3 = src4[192 + lane];

  const float vv[16] = {f0.x, f0.y, f0.z, f0.w, f1.x, f1.y, f1.z, f1.w,
                        f2.x, f2.y, f2.z, f2.w, f3.x, f3.y, f3.z, f3.w};

  // ---- wave-wide counts at 5 thresholds via independent ballots (SGPR sums)
  int C0 = 0, C1 = 0, C2 = 0, C3 = 0, C4 = 0;
#pragma unroll
  for (int j = 0; j < 16; ++j) {
    const float v = vv[j];
    C0 += (int)__popcll(__ballot(v < -0.125f));
    C1 += (int)__popcll(__ballot(v < -0.0625f));
    C2 += (int)__popcll(__ballot(v <  0.0f));
    C3 += (int)__popcll(__ballot(v <  0.0625f));
    C4 += (int)__popcll(__ballot(v <  0.125f));
  }

  // ---- scalar interval pick
  int ms = 0, r2 = 0;
  float tLo = 0.f, tHi = 0.f;
  bool fast = (C0 <= RANKK) && (RANKK < C4);
  if (fast) {
    int cl_, ch_;
    if (RANKK < C1)      { tLo = -0.125f;  tHi = -0.0625f; cl_ = C0; ch_ = C1; }
    else if (RANKK < C2) { tLo = -0.0625f; tHi =  0.0f;    cl_ = C1; ch_ = C2; }
    else if (RANKK < C3) { tLo =  0.0f;    tHi =  0.0625f; cl_ = C2; ch_ = C3; }
    else                 { tLo =  0.0625f; tHi =  0.125f;  cl_ = C3; ch_ = C4; }
    ms = ch_ - cl_;
    r2 = RANKK - cl_;
    fast = (ms <= 64);
  }

  if (fast) {
    // ---- ballot+mbcnt compact winning interval into cand[w][0..ms-1]
    unsigned base = 0;
#pragma unroll
    for (int j = 0; j < 16; ++j) {
      const bool match = (vv[j] >= tLo) && (vv[j] < tHi);
      const unsigned long long mk = __ballot(match);
      if (match) {
        const unsigned pos = __builtin_amdgcn_mbcnt_hi(
            (unsigned)(mk >> 32),
            __builtin_amdgcn_mbcnt_lo((unsigned)mk, 0u));
        cand[w][base + pos] = vv[j];
      }
      base += (unsigned)__popcll(mk);   // uniform -> SALU
    }
    if (lane < 4) cand[w][ms + lane] = inf;   // pad to x4 (ms+4 <= 68)
    const float myv = cand[w][lane];          // lanes >= ms: garbage, masked
    unsigned cl = 0, ce = 0;
    const int nq = (ms + 3) >> 2;             // scalar bound
    for (int q = 0; q < nq; ++q) {            // ds_read_b128 broadcast
      const float4 cq = *((const float4*)&cand[w][q << 2]);
      cl += (cq.x < myv) + (cq.y < myv) + (cq.z < myv) + (cq.w < myv);
      ce += (cq.x == myv) + (cq.y == myv) + (cq.z == myv) + (cq.w == myv);
    }
    if ((lane < ms) && (cl <= (unsigned)r2) && ((unsigned)r2 < cl + ce))
      med[row] = myv;                         // duplicates write same value
  } else {
    // ---- exact bitwise bisection on monotone keys (register-only, rare)
    unsigned key[16];
#pragma unroll
    for (int j = 0; j < 16; ++j) {
      const unsigned b = __float_as_uint(vv[j]);
      key[j] = (b & 0x80000000u) ? ~b : (b | 0x80000000u);
    }
    if (!v3) {        // pads -> max key, provably invisible to the search
#pragma unroll
      for (int j = 12; j < 16; ++j) key[j] = 0xFFFFFFFFu;
    }
    // largest X with count(key < X) <= RANKK  ==  key of rank-RANKK element
    unsigned ans = 0u;
    for (int bit = 31; bit >= 0; --bit) {
      const unsigned candd = ans | (1u << bit);
      int c = 0;
#pragma unroll
      for (int j = 0; j < 16; ++j)
        c += (int)__popcll(__ballot(key[j] < candd));
      if (c <= RANKK) ans = candd;
    }
    if (lane == 0) {
      const unsigned b = (ans & 0x80000000u) ? (ans & 0x7fffffffu) : ~ans;
      med[row] = __uint_as_float(b);
    }
  }
}

// ---------------- Kernel 2: split-k GEMM partials (r9 verbatim) --------------
#define KSP 192

__global__ __launch_bounds__(256) void gemm_partial(
    const float* __restrict__ med, const float* __restrict__ W,
    float* __restrict__ part) {
  __shared__ __align__(16) float Ws[32][196];  // stride 196: 196%32=4 ->
  __shared__ __align__(16) float Ms[32][196];  //  2-way aliasing only (free)

  const int tid = threadIdx.x;
  const int o0 = blockIdx.x * 32;      // 0..992 (o >= 1000 zero-padded)
  const int b0 = blockIdx.y * 32;      // 0..96
  const int k0 = blockIdx.z * KSP;     // 0..576

#pragma unroll
  for (int i = tid; i < 32 * 48; i += 256) {
    const int rw = i / 48, q = i % 48;
    const int o = o0 + rw;
    const float4 wv = (o < 1000)
        ? *(const float4*)&W[(size_t)o * 768 + k0 + 4 * q]
        : make_float4(0.f, 0.f, 0.f, 0.f);
    *(float4*)&Ws[rw][4 * q] = wv;
    *(float4*)&Ms[rw][4 * q] =
        *(const float4*)&med[(size_t)(b0 + rw) * 768 + k0 + 4 * q];
  }
  __syncthreads();

  const int to = tid & 15, tb = tid >> 4;
  float a00 = 0.f, a01 = 0.f, a10 = 0.f, a11 = 0.f;
#pragma unroll 4
  for (int c = 0; c < 48; ++c) {
    const float4 w0 = *(const float4*)&Ws[to][4 * c];
    const float4 w1 = *(const float4*)&Ws[to + 16][4 * c];
    const float4 m0 = *(const float4*)&Ms[tb][4 * c];
    const float4 m1 = *(const float4*)&Ms[tb + 16][4 * c];
    a00 = fmaf(w0.x, m0.x, a00); a00 = fmaf(w0.y, m0.y, a00);
    a00 = fmaf(w0.z, m0.z, a00); a00 = fmaf(w0.w, m0.w, a00);
    a10 = fmaf(w1.x, m0.x, a10); a10 = fmaf(w1.y, m0.y, a10);
    a10 = fmaf(w1.z, m0.z, a10); a10 = fmaf(w1.w, m0.w, a10);
    a01 = fmaf(w0.x, m1.x, a01); a01 = fmaf(w0.y, m1.y, a01);
    a01 = fmaf(w0.z, m1.z, a01); a01 = fmaf(w0.w, m1.w, a01);
    a11 = fmaf(w1.x, m1.x, a11); a11 = fmaf(w1.y, m1.y, a11);
    a11 = fmaf(w1.z, m1.z, a11); a11 = fmaf(w1.w, m1.w, a11);
  }

  float* p = part + (size_t)blockIdx.z * 131072;   // [128][1024] per split
  p[(size_t)(b0 + tb)      * 1024 + o0 + to]      = a00;
  p[(size_t)(b0 + tb)      * 1024 + o0 + to + 16] = a10;
  p[(size_t)(b0 + tb + 16) * 1024 + o0 + to]      = a01;
  p[(size_t)(b0 + tb + 16) * 1024 + o0 + to + 16] = a11;
}

// ---------------- Kernel 3: reduce 4 partials + bias -------------------------
__global__ __launch_bounds__(256) void reduce_bias_kernel(
    const float* __restrict__ part, const float* __restrict__ bias,
    float* __restrict__ out) {
  const int idx = blockIdx.x * 256 + threadIdx.x;   // over 128 x 1024
  const int b = idx >> 10, o = idx & 1023;
  if (o < 1000) {
    const float s = part[idx] + part[131072 + idx] +
                    part[262144 + idx] + part[393216 + idx];
    out[(size_t)b * 1000 + o] = s + bias[o];
  }
}

extern "C" void kernel_launch(void* const* d_in, const int* in_sizes, int n_in,
                              void* d_out, int out_size, void* d_ws, size_t ws_size,
                              hipStream_t stream) {
  const float* x = (const float*)d_in[0];    // [128,768,28,28]
  const float* W = (const float*)d_in[1];    // [1000,768]
  const float* b = (const float*)d_in[2];    // [1000]
  float* out = (float*)d_out;                // [128,1000]
  float* med = (float*)d_ws;                 // [128,768] f32
  float* part = med + 128 * 768;             // [4][128][1024] f32 partials

  const int rows = 128 * 768;                // 98304
  kth_select_kernel<<<rows / NWAVE, 256, 0, stream>>>(x, med);

  dim3 g2(32, 4, 4);                         // 512 blocks
  gemm_partial<<<g2, 256, 0, stream>>>(med, W, part);

  reduce_bias_kernel<<<512, 256, 0, stream>>>(part, b, out);
}

// Round 11
// 70.830 us; speedup vs baseline: 1.3492x; 1.3492x over previous
//
#include <hip/hip_runtime.h>
#include <hip/hip_bf16.h>

// x[128][768][28][28] f32 -> per-(b,c) ascending-rank-392 of 784 values,
// then med[128][768] @ W[1000][768]^T + bias -> out[128][1000].

#define NROW 784
#define RANKK 392u
#define NWAVE 4   // rows (waves) per block

// ---------------- Kernel 1: per-wave exact select ----------------------------
// r4/r9 skeleton (best measured). Two targeted changes:
//  (1) compaction: atomic-append -> ballot+mbcnt (kills 16 same-address
//      atomic-return round-trips; only 16 ballots, below SALU-chain pain)
//  (2) finisher: scalar loop bound via readfirstlane + float4 LDS broadcasts
//      (3 reads instead of ~10 serial scalar broadcasts w/ VGPR bound)
// cand[] now stores floats; radix fallback (never taken on this data, exact
// for any data) converts float->sortable key on the fly.
__global__ __launch_bounds__(256) void kth_select_kernel(
    const float* __restrict__ x, float* __restrict__ med) {
  __shared__ __align__(16) float cand[NWAVE][NROW];  // 12544 B
  __shared__ unsigned hist[NWAVE][4][65];            // 4160 B (bank-staggered)
  __shared__ unsigned apcnt[NWAVE];                  // fallback only

  const int tid  = threadIdx.x;
  const int lane = tid & 63;
  const int w    = tid >> 6;
  const int row  = blockIdx.x * NWAVE + w;
  const float4* src4 = (const float4*)(x + (size_t)row * NROW);
  const int sub = lane & 3;
  const float inf = __int_as_float(0x7f800000);

  // ---- load row: 196 float4 spread as {lane, 64+lane, 128+lane, 192+lane<4}
  float4 f0 = src4[lane];
  float4 f1 = src4[64 + lane];
  float4 f2 = src4[128 + lane];
  const bool v3 = (lane < 4);
  float4 f3 = make_float4(0.f, 0.f, 0.f, 0.f);
  if (v3) f3 = src4[192 + lane];

  const float vv[16] = {f0.x, f0.y, f0.z, f0.w, f1.x, f1.y, f1.z, f1.w,
                        f2.x, f2.y, f2.z, f2.w, f3.x, f3.y, f3.z, f3.w};

  // ---- buckets: clamp(floor(32v)+32, 0, 63)  (r4-identical)
  int bkt[16];
#pragma unroll
  for (int j = 0; j < 16; ++j) {
    const int bi = __float2int_rd(fmaf(vv[j], 32.f, 32.f));
    bkt[j] = min(max(bi, 0), 63);
  }

  // ---- histogram: 4 bank-staggered sub-hists, wave-private (r4-identical)
#pragma unroll
  for (int s = 0; s < 4; ++s) hist[w][s][lane] = 0u;
#pragma unroll
  for (int j = 0; j < 12; ++j) atomicAdd(&hist[w][sub][bkt[j]], 1u);
  if (v3) {
#pragma unroll
    for (int j = 12; j < 16; ++j) atomicAdd(&hist[w][sub][bkt[j]], 1u);
  }

  // ---- scan + winning bucket (r4-identical)
  unsigned r = RANKK;
  unsigned m;
  int D;
  {
    unsigned cnt = hist[w][0][lane] + hist[w][1][lane] + hist[w][2][lane] + hist[w][3][lane];
    unsigned incl = cnt;
#pragma unroll
    for (int off = 1; off < 64; off <<= 1) {
      unsigned t = __shfl_up(incl, off, 64);
      if (lane >= off) incl += t;
    }
    const unsigned excl = incl - cnt;
    const bool hit = (r >= excl) && (r < incl);
    const unsigned long long hm = __ballot(hit);
    D = __ffsll(hm) - 1;
    r -= __shfl(excl, D, 64);
    m  = __shfl(cnt,  D, 64);
  }

  // ---- compaction: ballot+mbcnt (CHANGE 1), stores floats
  {
    unsigned base = 0;
#pragma unroll
    for (int j = 0; j < 16; ++j) {
      const bool va = (j < 12) || v3;
      const bool match = va && (bkt[j] == D);
      const unsigned long long mk = __ballot(match);
      if (match) {
        const unsigned pos = __builtin_amdgcn_mbcnt_hi(
            (unsigned)(mk >> 32),
            __builtin_amdgcn_mbcnt_lo((unsigned)mk, 0u));
        cand[w][base + pos] = vv[j];
      }
      base += (unsigned)__popcll(mk);   // uniform -> SALU
    }
  }

  // ---- fallback: exact MSB 6-bit radix refinement (only if m > 64) ---------
#pragma unroll 1
  for (int p = 0; p < 6; ++p) {
    if (m <= 64u) break;
    const int shift = (p < 5) ? (26 - 6 * p) : 0;
#pragma unroll
    for (int s = 0; s < 4; ++s) hist[w][s][lane] = 0u;
    const int nch = (int)((m + 63u) >> 6);
    for (int c = 0; c < nch; ++c) {
      const int idx = (c << 6) + lane;
      if (idx < (int)m) {
        const unsigned b = __float_as_uint(cand[w][idx]);
        const unsigned key = (b & 0x80000000u) ? ~b : (b | 0x80000000u);
        atomicAdd(&hist[w][sub][(key >> shift) & 63u], 1u);
      }
    }
    unsigned cnt = hist[w][0][lane] + hist[w][1][lane] + hist[w][2][lane] + hist[w][3][lane];
    unsigned incl = cnt;
#pragma unroll
    for (int off = 1; off < 64; off <<= 1) {
      unsigned t = __shfl_up(incl, off, 64);
      if (lane >= off) incl += t;
    }
    const unsigned excl = incl - cnt;
    const bool hit = (r >= excl) && (r < incl);
    const unsigned long long hm = __ballot(hit);
    const int Dp = __ffsll(hm) - 1;
    r -= __shfl(excl, Dp, 64);
    const unsigned m2 = __shfl(cnt, Dp, 64);
    // in-place append compact: chunk fully read before writes; append index
    // <= read index -> safe (r4-proven).
    if (lane == 0) apcnt[w] = 0u;
    for (int c = 0; c < nch; ++c) {
      const int idx = (c << 6) + lane;
      const bool va = idx < (int)m;
      const float f = va ? cand[w][idx] : 0.f;
      const unsigned b = __float_as_uint(f);
      const unsigned key = (b & 0x80000000u) ? ~b : (b | 0x80000000u);
      if (va && (((key >> shift) & 63u) == (unsigned)Dp)) {
        const unsigned slot = atomicAdd(&apcnt[w], 1u);
        cand[w][slot] = f;
      }
    }
    m = m2;
  }

  // ---- finisher (CHANGE 2): scalar bounds + float4 broadcasts --------------
  if (m > 64u) {
    // radix exhausted all 32 key bits -> remaining candidates identical
    if (lane == 0) med[row] = cand[w][0];
  } else {
    const int ms = __builtin_amdgcn_readfirstlane((int)m);
    const int rs = __builtin_amdgcn_readfirstlane((int)r);
    if (lane < 4) cand[w][ms + lane] = inf;     // pad to x4 (ms+4 <= 68 < 784)
    const float myv = cand[w][lane];            // lanes >= ms: garbage, masked
    unsigned cl = 0, ce = 0;
    const int nq = (ms + 3) >> 2;               // scalar loop bound
    for (int q = 0; q < nq; ++q) {              // ds_read_b128 broadcast
      const float4 cq = *((const float4*)&cand[w][q << 2]);
      cl += (cq.x < myv) + (cq.y < myv) + (cq.z < myv) + (cq.w < myv);
      ce += (cq.x == myv) + (cq.y == myv) + (cq.z == myv) + (cq.w == myv);
    }
    if ((lane < ms) && (cl <= (unsigned)rs) && ((unsigned)rs < cl + ce))
      med[row] = myv;                           // duplicates write same value
  }
}

// ---------------- Kernel 2: split-k GEMM partials (r9 verbatim) --------------
#define KSP 192

__global__ __launch_bounds__(256) void gemm_partial(
    const float* __restrict__ med, const float* __restrict__ W,
    float* __restrict__ part) {
  __shared__ __align__(16) float Ws[32][196];  // stride 196: 196%32=4 ->
  __shared__ __align__(16) float Ms[32][196];  //  2-way aliasing only (free)

  const int tid = threadIdx.x;
  const int o0 = blockIdx.x * 32;      // 0..992 (o >= 1000 zero-padded)
  const int b0 = blockIdx.y * 32;      // 0..96
  const int k0 = blockIdx.z * KSP;     // 0..576

#pragma unroll
  for (int i = tid; i < 32 * 48; i += 256) {
    const int rw = i / 48, q = i % 48;
    const int o = o0 + rw;
    const float4 wv = (o < 1000)
        ? *(const float4*)&W[(size_t)o * 768 + k0 + 4 * q]
        : make_float4(0.f, 0.f, 0.f, 0.f);
    *(float4*)&Ws[rw][4 * q] = wv;
    *(float4*)&Ms[rw][4 * q] =
        *(const float4*)&med[(size_t)(b0 + rw) * 768 + k0 + 4 * q];
  }
  __syncthreads();

  const int to = tid & 15, tb = tid >> 4;
  float a00 = 0.f, a01 = 0.f, a10 = 0.f, a11 = 0.f;
#pragma unroll 4
  for (int c = 0; c < 48; ++c) {
    const float4 w0 = *(const float4*)&Ws[to][4 * c];
    const float4 w1 = *(const float4*)&Ws[to + 16][4 * c];
    const float4 m0 = *(const float4*)&Ms[tb][4 * c];
    const float4 m1 = *(const float4*)&Ms[tb + 16][4 * c];
    a00 = fmaf(w0.x, m0.x, a00); a00 = fmaf(w0.y, m0.y, a00);
    a00 = fmaf(w0.z, m0.z, a00); a00 = fmaf(w0.w, m0.w, a00);
    a10 = fmaf(w1.x, m0.x, a10); a10 = fmaf(w1.y, m0.y, a10);
    a10 = fmaf(w1.z, m0.z, a10); a10 = fmaf(w1.w, m0.w, a10);
    a01 = fmaf(w0.x, m1.x, a01); a01 = fmaf(w0.y, m1.y, a01);
    a01 = fmaf(w0.z, m1.z, a01); a01 = fmaf(w0.w, m1.w, a01);
    a11 = fmaf(w1.x, m1.x, a11); a11 = fmaf(w1.y, m1.y, a11);
    a11 = fmaf(w1.z, m1.z, a11); a11 = fmaf(w1.w, m1.w, a11);
  }

  float* p = part + (size_t)blockIdx.z * 131072;   // [128][1024] per split
  p[(size_t)(b0 + tb)      * 1024 + o0 + to]      = a00;
  p[(size_t)(b0 + tb)      * 1024 + o0 + to + 16] = a10;
  p[(size_t)(b0 + tb + 16) * 1024 + o0 + to]      = a01;
  p[(size_t)(b0 + tb + 16) * 1024 + o0 + to + 16] = a11;
}

// ---------------- Kernel 3: reduce 4 partials + bias -------------------------
__global__ __launch_bounds__(256) void reduce_bias_kernel(
    const float* __restrict__ part, const float* __restrict__ bias,
    float* __restrict__ out) {
  const int idx = blockIdx.x * 256 + threadIdx.x;   // over 128 x 1024
  const int b = idx >> 10, o = idx & 1023;
  if (o < 1000) {
    const float s = part[idx] + part[131072 + idx] +
                    part[262144 + idx] + part[393216 + idx];
    out[(size_t)b * 1000 + o] = s + bias[o];
  }
}

extern "C" void kernel_launch(void* const* d_in, const int* in_sizes, int n_in,
                              void* d_out, int out_size, void* d_ws, size_t ws_size,
                              hipStream_t stream) {
  const float* x = (const float*)d_in[0];    // [128,768,28,28]
  const float* W = (const float*)d_in[1];    // [1000,768]
  const float* b = (const float*)d_in[2];    // [1000]
  float* out = (float*)d_out;                // [128,1000]
  float* med = (float*)d_ws;                 // [128,768] f32
  float* part = med + 128 * 768;             // [4][128][1024] f32 partials

  const int rows = 128 * 768;                // 98304
  kth_select_kernel<<<rows / NWAVE, 256, 0, stream>>>(x, med);

  dim3 g2(32, 4, 4);                         // 512 blocks
  gemm_partial<<<g2, 256, 0, stream>>>(med, W, part);

  reduce_bias_kernel<<<512, 256, 0, stream>>>(part, b, out);
}

// Round 12
// 64.089 us; speedup vs baseline: 1.4911x; 1.1052x over previous
//
#include <hip/hip_runtime.h>
#include <hip/hip_bf16.h>

// x[128][768][28][28] f32 -> per-(b,c) ascending-rank-392 of 784 values,
// then med[128][768] @ W[1000][768]^T + bias -> out[128][1000].

#define NROW 784
#define RANKK 392u
#define NWAVE 4   // rows (waves) per block

// Wave64 inclusive add-scan via DPP (row_shr 1/2/4/8 + bcast15/31) — pure
// VALU, replaces 6 ds_bpermute-based __shfl_up. Standard GCN pattern.
__device__ __forceinline__ unsigned wave_scan_add(unsigned x) {
  x += (unsigned)__builtin_amdgcn_update_dpp(0, (int)x, 0x111, 0xf, 0xf, true);
  x += (unsigned)__builtin_amdgcn_update_dpp(0, (int)x, 0x112, 0xf, 0xf, true);
  x += (unsigned)__builtin_amdgcn_update_dpp(0, (int)x, 0x114, 0xf, 0xf, true);
  x += (unsigned)__builtin_amdgcn_update_dpp(0, (int)x, 0x118, 0xf, 0xf, true);
  x += (unsigned)__builtin_amdgcn_update_dpp(0, (int)x, 0x142, 0xa, 0xf, true);
  x += (unsigned)__builtin_amdgcn_update_dpp(0, (int)x, 0x143, 0xc, 0xf, true);
  return x;
}

// ---------------- Kernel 1: per-wave exact select ----------------------------
// r11 skeleton. Changes: (1) DPP scan + readlane extraction (scan leaves DS
// pipe; m,r become SGPRs naturally); (2) hist[64][4] layout: zero = 1
// ds_write_b128, count read = 1 ds_read_b128 (was 8 b32 ops); buckets packed
// 4x8bit in 4 u32; (3) bias-init for `out` folded into blocks 0..499.
// DS ops/row ~41 (was ~51). Exact MSB-radix fallback for m>64 retained.
__global__ __launch_bounds__(256) void kth_select_kernel(
    const float* __restrict__ x, float* __restrict__ med,
    const float* __restrict__ bias, float* __restrict__ out) {
  __shared__ __align__(16) float cand[NWAVE][NROW];   // 12544 B
  __shared__ __align__(16) unsigned hist[NWAVE][64][4];  // 4096 B
  __shared__ unsigned apcnt[NWAVE];

  const int tid  = threadIdx.x;
  const int lane = tid & 63;
  const int w    = tid >> 6;
  const int row  = blockIdx.x * NWAVE + w;
  const float4* src4 = (const float4*)(x + (size_t)row * NROW);
  const int sub = lane & 3;
  const float inf = __int_as_float(0x7f800000);

  // ---- fused bias-init of out[128][1000] (128000 = 500 blocks x 256)
  if (blockIdx.x < 500) {
    const int idx = blockIdx.x * 256 + tid;
    out[idx] = bias[idx % 1000];
  }

  // ---- load row: 196 float4 spread as {lane, 64+lane, 128+lane, 192+lane<4}
  float4 f0 = src4[lane];
  float4 f1 = src4[64 + lane];
  float4 f2 = src4[128 + lane];
  const bool v3 = (lane < 4);
  float4 f3 = make_float4(0.f, 0.f, 0.f, 0.f);
  if (v3) f3 = src4[192 + lane];

  const float vv[16] = {f0.x, f0.y, f0.z, f0.w, f1.x, f1.y, f1.z, f1.w,
                        f2.x, f2.y, f2.z, f2.w, f3.x, f3.y, f3.z, f3.w};

  // ---- zero hist: ONE wave-wide ds_write_b128 (64 lanes x 16B = 1024B)
  ((uint4*)&hist[w][0][0])[lane] = make_uint4(0u, 0u, 0u, 0u);

  // ---- histogram: bucket = clamp(floor(32v)+32,0,63); pack 4x8b into bpk[]
  unsigned bpk[4] = {0u, 0u, 0u, 0u};
#pragma unroll
  for (int j = 0; j < 16; ++j) {
    const bool va = (j < 12) || v3;
    const int bi = min(max(__float2int_rd(fmaf(vv[j], 32.f, 32.f)), 0), 63);
    bpk[j >> 2] |= (unsigned)bi << (8 * (j & 3));
    if (va) atomicAdd(&hist[w][bi][sub], 1u);
  }

  // ---- count read: ONE ds_read_b128 per lane; DPP scan; readlane extract
  unsigned r, m;
  int D;
  {
    const uint4 hv = ((const uint4*)&hist[w][0][0])[lane];
    const unsigned cnt = hv.x + hv.y + hv.z + hv.w;
    const unsigned incl = wave_scan_add(cnt);
    const unsigned excl = incl - cnt;
    const bool hit = (RANKK >= excl) && (RANKK < incl);
    const unsigned long long hm = __ballot(hit);
    D = __ffsll(hm) - 1;                              // SGPR
    r = RANKK - (unsigned)__builtin_amdgcn_readlane((int)excl, D);
    m = (unsigned)__builtin_amdgcn_readlane((int)cnt, D);   // SGPRs
  }

  // ---- compaction: ballot+mbcnt, bucket from packed bpk (bfe)
  {
    unsigned base = 0;
#pragma unroll
    for (int j = 0; j < 16; ++j) {
      const bool va = (j < 12) || v3;
      const unsigned bj = (bpk[j >> 2] >> (8 * (j & 3))) & 0xffu;
      const bool match = va && (bj == (unsigned)D);
      const unsigned long long mk = __ballot(match);
      if (match) {
        const unsigned pos = __builtin_amdgcn_mbcnt_hi(
            (unsigned)(mk >> 32),
            __builtin_amdgcn_mbcnt_lo((unsigned)mk, 0u));
        cand[w][base + pos] = vv[j];
      }
      base += (unsigned)__popcll(mk);   // uniform -> SALU
    }
  }

  // ---- fallback: exact MSB 6-bit radix refinement (only if m > 64) ---------
#pragma unroll 1
  for (int p = 0; p < 6; ++p) {
    if (m <= 64u) break;
    const int shift = (p < 5) ? (26 - 6 * p) : 0;
    ((uint4*)&hist[w][0][0])[lane] = make_uint4(0u, 0u, 0u, 0u);
    const int nch = (int)((m + 63u) >> 6);
    for (int c = 0; c < nch; ++c) {
      const int idx = (c << 6) + lane;
      if (idx < (int)m) {
        const unsigned b = __float_as_uint(cand[w][idx]);
        const unsigned key = (b & 0x80000000u) ? ~b : (b | 0x80000000u);
        atomicAdd(&hist[w][(key >> shift) & 63u][sub], 1u);
      }
    }
    const uint4 h2 = ((const uint4*)&hist[w][0][0])[lane];
    const unsigned c2 = h2.x + h2.y + h2.z + h2.w;
    const unsigned i2 = wave_scan_add(c2);
    const unsigned e2 = i2 - c2;
    const bool hit2 = (r >= e2) && (r < i2);
    const unsigned long long hm2 = __ballot(hit2);
    const int Dp = __ffsll(hm2) - 1;
    r -= (unsigned)__builtin_amdgcn_readlane((int)e2, Dp);
    const unsigned m2 = (unsigned)__builtin_amdgcn_readlane((int)c2, Dp);
    // in-place append compact: chunk fully read before writes; append index
    // <= read index -> safe (r4-proven).
    if (lane == 0) apcnt[w] = 0u;
    for (int c = 0; c < nch; ++c) {
      const int idx = (c << 6) + lane;
      const bool va2 = idx < (int)m;
      const float f = va2 ? cand[w][idx] : 0.f;
      const unsigned b = __float_as_uint(f);
      const unsigned key = (b & 0x80000000u) ? ~b : (b | 0x80000000u);
      if (va2 && (((key >> shift) & 63u) == (unsigned)Dp)) {
        const unsigned slot = atomicAdd(&apcnt[w], 1u);
        cand[w][slot] = f;
      }
    }
    m = m2;
  }

  // ---- finisher: scalar bounds (m,r already SGPR) + float4 broadcasts ------
  if (m > 64u) {
    // radix exhausted all 32 key bits -> remaining candidates identical
    if (lane == 0) med[row] = cand[w][0];
  } else {
    const int ms = (int)m;
    const int rs = (int)r;
    if (lane < 4) cand[w][ms + lane] = inf;     // pad to x4 (ms+4 <= 68 < 784)
    const float myv = cand[w][lane];            // lanes >= ms: garbage, masked
    unsigned cl = 0, ce = 0;
    const int nq = (ms + 3) >> 2;               // scalar loop bound
    for (int q = 0; q < nq; ++q) {              // ds_read_b128 broadcast
      const float4 cq = *((const float4*)&cand[w][q << 2]);
      cl += (cq.x < myv) + (cq.y < myv) + (cq.z < myv) + (cq.w < myv);
      ce += (cq.x == myv) + (cq.y == myv) + (cq.z == myv) + (cq.w == myv);
    }
    if ((lane < ms) && (cl <= (unsigned)rs) && ((unsigned)rs < cl + ce))
      med[row] = myv;                           // duplicates write same value
  }
}

// ---------------- Kernel 2: split-k GEMM, atomic epilogue --------------------
// r9 tile (32o x 32b x 192k, 2x2/thread, all-float4 LDS). Partial results
// atomicAdd'ed straight into out (pre-initialized with bias by kernel 1):
// kills the reduce dispatch + 4MB of partials traffic. 4 adds/address.
#define KSP 192

__global__ __launch_bounds__(256) void gemm_atomic(
    const float* __restrict__ med, const float* __restrict__ W,
    float* __restrict__ out) {
  __shared__ __align__(16) float Ws[32][196];  // stride 196: 196%32=4 ->
  __shared__ __align__(16) float Ms[32][196];  //  2-way aliasing only (free)

  const int tid = threadIdx.x;
  const int o0 = blockIdx.x * 32;      // 0..992 (o >= 1000 zero-padded)
  const int b0 = blockIdx.y * 32;      // 0..96
  const int k0 = blockIdx.z * KSP;     // 0..576

#pragma unroll
  for (int i = tid; i < 32 * 48; i += 256) {
    const int rw = i / 48, q = i % 48;
    const int o = o0 + rw;
    const float4 wv = (o < 1000)
        ? *(const float4*)&W[(size_t)o * 768 + k0 + 4 * q]
        : make_float4(0.f, 0.f, 0.f, 0.f);
    *(float4*)&Ws[rw][4 * q] = wv;
    *(float4*)&Ms[rw][4 * q] =
        *(const float4*)&med[(size_t)(b0 + rw) * 768 + k0 + 4 * q];
  }
  __syncthreads();

  const int to = tid & 15, tb = tid >> 4;
  float a00 = 0.f, a01 = 0.f, a10 = 0.f, a11 = 0.f;
#pragma unroll 4
  for (int c = 0; c < 48; ++c) {
    const float4 w0 = *(const float4*)&Ws[to][4 * c];
    const float4 w1 = *(const float4*)&Ws[to + 16][4 * c];
    const float4 m0 = *(const float4*)&Ms[tb][4 * c];
    const float4 m1 = *(const float4*)&Ms[tb + 16][4 * c];
    a00 = fmaf(w0.x, m0.x, a00); a00 = fmaf(w0.y, m0.y, a00);
    a00 = fmaf(w0.z, m0.z, a00); a00 = fmaf(w0.w, m0.w, a00);
    a10 = fmaf(w1.x, m0.x, a10); a10 = fmaf(w1.y, m0.y, a10);
    a10 = fmaf(w1.z, m0.z, a10); a10 = fmaf(w1.w, m0.w, a10);
    a01 = fmaf(w0.x, m1.x, a01); a01 = fmaf(w0.y, m1.y, a01);
    a01 = fmaf(w0.z, m1.z, a01); a01 = fmaf(w0.w, m1.w, a01);
    a11 = fmaf(w1.x, m1.x, a11); a11 = fmaf(w1.y, m1.y, a11);
    a11 = fmaf(w1.z, m1.z, a11); a11 = fmaf(w1.w, m1.w, a11);
  }

  const int ra = (b0 + tb) * 1000;
  const int rb = (b0 + tb + 16) * 1000;
  const int oA = o0 + to, oB = o0 + to + 16;
  if (oA < 1000) {
    atomicAdd(&out[ra + oA], a00);
    atomicAdd(&out[rb + oA], a01);
  }
  if (oB < 1000) {
    atomicAdd(&out[ra + oB], a10);
    atomicAdd(&out[rb + oB], a11);
  }
}

extern "C" void kernel_launch(void* const* d_in, const int* in_sizes, int n_in,
                              void* d_out, int out_size, void* d_ws, size_t ws_size,
                              hipStream_t stream) {
  const float* x = (const float*)d_in[0];    // [128,768,28,28]
  const float* W = (const float*)d_in[1];    // [1000,768]
  const float* b = (const float*)d_in[2];    // [1000]
  float* out = (float*)d_out;                // [128,1000]
  float* med = (float*)d_ws;                 // [128,768] f32

  const int rows = 128 * 768;                // 98304 -> 24576 blocks
  kth_select_kernel<<<rows / NWAVE, 256, 0, stream>>>(x, med, b, out);

  dim3 g2(32, 4, 4);                         // 512 blocks
  gemm_atomic<<<g2, 256, 0, stream>>>(med, W, out);
}